// Round 5
// baseline (881.135 us; speedup 1.0000x reference)
//
#include <hip/hip_runtime.h>
#include <cstdio>

// Qwen2 MoE sparse block, MI355X gfx950.
// Round 5: 8-phase 256x256 GEMM with INLINE-ASM ds_read_b128 in the K-loop
// (hypothesis: compiler-inserted vmcnt(0) before C-deref ds_reads after
// global_load_lds was draining the pipeline every phase). Rule-18 fencing:
// lgkmcnt(0) + sched_barrier(0) before each MFMA cluster. Shared-down now
// split-K=4 with atomic f32 accumulate into zeroed d_out.

#define H_DIM 2048
#define IMOE  1408
#define ISH   5632
#define NEXP  8
#define T_TOK 2048
#define TK_TOT (T_TOK * 2)

typedef __attribute__((ext_vector_type(8))) short short8;
typedef __attribute__((ext_vector_type(8))) __bf16 bf16x8;
typedef __attribute__((ext_vector_type(4))) float f32x4;

__device__ __forceinline__ float bf2f(unsigned short u) {
  union { unsigned int i; float f; } v; v.i = ((unsigned int)u) << 16; return v.f;
}
__device__ __forceinline__ unsigned short f2bf(float f) {
  union { float f; unsigned int i; } v; v.f = f;
  unsigned int x = v.i;
  return (unsigned short)((x + 0x7fffu + ((x >> 16) & 1u)) >> 16);
}

__device__ __forceinline__ f32x4 MFMA16(short8 a, short8 b, f32x4 c) {
  return __builtin_amdgcn_mfma_f32_16x16x32_bf16(
      __builtin_bit_cast(bf16x8, a), __builtin_bit_cast(bf16x8, b), c, 0, 0, 0);
}

__device__ __forceinline__ void gload_lds16(const unsigned short* g, unsigned short* l) {
  __builtin_amdgcn_global_load_lds(
      (const __attribute__((address_space(1))) unsigned int*)g,
      (__attribute__((address_space(3))) unsigned int*)l, 16, 0, 0);
}

__device__ __forceinline__ float silu_f(float x) { return x / (1.0f + __expf(-x)); }

#define SBAR()   asm volatile("s_barrier" ::: "memory")
#define VMCNT(n) asm volatile("s_waitcnt vmcnt(" #n ")" ::: "memory")
#define LGKM0()  asm volatile("s_waitcnt lgkmcnt(0)" ::: "memory")
// inline-asm LDS read: addr is a 32-bit LDS byte address in a VGPR
#define DSR(dst, a) asm volatile("ds_read_b128 %0, %1" : "=v"(dst) : "v"(a))

// ---------------- conversion kernels ----------------

__global__ __launch_bounds__(256)
void transpose_cvt_kernel(const float* __restrict__ src, unsigned short* __restrict__ dst,
                          int R, int C, long sStride, long dStride) {
  src += (long)blockIdx.z * sStride;
  dst += (long)blockIdx.z * dStride;
  __shared__ float tile[32][33];
  int tx = threadIdx.x, ty = threadIdx.y;           // 32 x 8
  int x = blockIdx.x * 32 + tx;
  int yb = blockIdx.y * 32;
#pragma unroll
  for (int j = 0; j < 4; j++) {
    int y = yb + ty + j * 8;
    tile[ty + j * 8][tx] = src[(long)y * C + x];
  }
  __syncthreads();
  int c = blockIdx.x * 32 + ty;
  int r = yb + tx;
#pragma unroll
  for (int j = 0; j < 4; j++) {
    dst[(long)(c + j * 8) * R + r] = f2bf(tile[tx][ty + j * 8]);
  }
}

__global__ __launch_bounds__(256)
void cvt_x_kernel(const float* __restrict__ x, unsigned short* __restrict__ xb, int total4) {
  int i = blockIdx.x * 256 + threadIdx.x;
  if (i >= total4) return;
  float4 v = ((const float4*)x)[i];
  ushort4 o;
  o.x = f2bf(v.x); o.y = f2bf(v.y); o.z = f2bf(v.z); o.w = f2bf(v.w);
  ((ushort4*)xb)[i] = o;
}

// ---------------- routing ----------------

__global__ __launch_bounds__(256)
void router_kernel(const float* __restrict__ x, const float* __restrict__ Wr,
                   const float* __restrict__ Wsg, float* __restrict__ rw,
                   int* __restrict__ sel, float* __restrict__ sgate_sig,
                   int* __restrict__ counts) {
  int t = blockIdx.x;
  const float* xr = x + (long)t * H_DIM;
  float p[9];
#pragma unroll
  for (int e = 0; e < 9; e++) p[e] = 0.0f;
  for (int h = threadIdx.x; h < H_DIM; h += 256) {
    float xv = xr[h];
#pragma unroll
    for (int e = 0; e < 8; e++) p[e] += xv * Wr[e * H_DIM + h];
    p[8] += xv * Wsg[h];
  }
#pragma unroll
  for (int e = 0; e < 9; e++)
    for (int off = 32; off > 0; off >>= 1)
      p[e] += __shfl_down(p[e], off, 64);
  __shared__ float red[4][9];
  int wave = threadIdx.x >> 6, lane = threadIdx.x & 63;
  if (lane == 0) {
#pragma unroll
    for (int e = 0; e < 9; e++) red[wave][e] = p[e];
  }
  __syncthreads();
  if (threadIdx.x == 0) {
    float lg[9];
#pragma unroll
    for (int e = 0; e < 9; e++) lg[e] = red[0][e] + red[1][e] + red[2][e] + red[3][e];
    float m = lg[0];
#pragma unroll
    for (int e = 1; e < 8; e++) m = fmaxf(m, lg[e]);
    float pr[8], s = 0.0f;
#pragma unroll
    for (int e = 0; e < 8; e++) { pr[e] = expf(lg[e] - m); s += pr[e]; }
    float inv = 1.0f / s;
#pragma unroll
    for (int e = 0; e < 8; e++) pr[e] *= inv;
    int i0 = 0;
#pragma unroll
    for (int e = 1; e < 8; e++) if (pr[e] > pr[i0]) i0 = e;
    int i1 = (i0 == 0) ? 1 : 0;
#pragma unroll
    for (int e = 0; e < 8; e++) if (e != i0 && pr[e] > pr[i1]) i1 = e;
    rw[t * 2] = pr[i0]; rw[t * 2 + 1] = pr[i1];
    sel[t * 2] = i0;    sel[t * 2 + 1] = i1;
    sgate_sig[t] = 1.0f / (1.0f + expf(-lg[8]));
    atomicAdd(&counts[i0], 1);
    atomicAdd(&counts[i1], 1);
  }
}

__global__ void scan_kernel(const int* __restrict__ counts, int* __restrict__ offsets) {
  if (threadIdx.x == 0 && blockIdx.x == 0) {
    int s = 0;
    for (int e = 0; e < NEXP; e++) { offsets[e] = s; s += counts[e]; }
    offsets[NEXP] = s;
  }
}

__global__ __launch_bounds__(256)
void scatter_kernel(const int* __restrict__ sel, const int* __restrict__ offsets,
                    int* __restrict__ cursor, int* __restrict__ tok_of_slot,
                    int* __restrict__ slot_of_tok) {
  int t = blockIdx.x * 256 + threadIdx.x;
  if (t >= T_TOK) return;
#pragma unroll
  for (int k = 0; k < 2; k++) {
    int e = sel[t * 2 + k];
    int pos = atomicAdd(&cursor[e], 1);
    int slot = offsets[e] + pos;
    tok_of_slot[slot] = t;
    slot_of_tok[t * 2 + k] = slot;
  }
}

__global__ __launch_bounds__(256)
void gather_kernel(const unsigned short* __restrict__ xbf, const int* __restrict__ tok,
                   unsigned short* __restrict__ xg) {
  int i = blockIdx.x * 256 + threadIdx.x;   // slot*256 + col16B
  int slot = i >> 8, c8 = i & 255;
  long src = (long)tok[slot] * H_DIM + c8 * 8;
  ulonglong2 v = *(const ulonglong2*)(xbf + src);
  ((ulonglong2*)xg)[i] = v;
}

// ---------------- 256x256 8-phase GEMM, asm ds_read K-loop ----------------
// C[M,N] = A[M,K](bf16) * BT[N,K]^T(bf16).  512 thr = 8 waves (2M x 4N),
// wave tile 128x64. BK=64, LDS: A[2dbuf][2half][128][64] + B same = 128 KiB.
// 16B-granule swizzle g ^= (row&7): inverse on per-lane global source,
// forward on the asm ds_read address. Phase = {asm ds_reads; stage (2x
// gload_lds); s_barrier; lgkmcnt(0); sched_barrier(0); setprio(1); 16 MFMA;
// setprio(0); s_barrier}. Counted vmcnt(4) only at phases 3 and 7.
template <int PHASE>
__global__ __launch_bounds__(512, 2)
void moe_gemm8_kernel(const unsigned short* __restrict__ Ash,
                      const unsigned short* __restrict__ Bsh,
                      const unsigned short* __restrict__ Aex,
                      const unsigned short* __restrict__ Bex,
                      void* __restrict__ Csh, void* __restrict__ Cex,
                      const int* __restrict__ counts,
                      const int* __restrict__ offsets,
                      const float* __restrict__ rowscale) {
  // XCD-aware bijective swizzle (grid % 8 == 0)
  int o = blockIdx.x;
  int b = (o & 7) * (gridDim.x >> 3) + (o >> 3);

  const unsigned short *A, *B;
  char* Cc;
  int N, Kld, NT, row0, col0, rowbase = 0, cnt, k0 = 0;
  int epi;   // 0 bf16, 1 f32 atomic * rowscale, 2 f32
  if constexpr (PHASE == 0) {
    if (b < 352) {                       // shared gate-up: 8 x 44
      A = Ash; B = Bsh; Cc = (char*)Csh; epi = 0;
      N = 2 * ISH; Kld = H_DIM; NT = H_DIM / 64;
      row0 = (b & 7) * 256; col0 = (b >> 3) * 256; cnt = T_TOK;
    } else {                             // expert gate-up: 8 x 11 per expert
      int b2 = b - 352, e = b2 / 88, r2 = b2 % 88;
      cnt = counts[e]; row0 = (r2 & 7) * 256;
      if (row0 >= cnt) return;
      rowbase = offsets[e];
      A = Aex; B = Bex + (long)e * 2 * IMOE * H_DIM; Cc = (char*)Cex; epi = 0;
      N = 2 * IMOE; Kld = H_DIM; NT = H_DIM / 64;
      col0 = (r2 >> 3) * 256;
    }
  } else {
    if (b < 256) {                       // shared down: 8 x 8 x splitK4, atomic
      A = Ash; B = Bsh; Cc = (char*)Csh; epi = 1;
      N = H_DIM; Kld = ISH; NT = (ISH / 4) / 64;
      row0 = (b & 7) * 256; col0 = ((b >> 3) & 7) * 256; cnt = T_TOK;
      k0 = (b >> 6) * (ISH / 4);
    } else {                             // expert down: 8 x 8 per expert
      int b2 = b - 256, e = b2 >> 6, r2 = b2 & 63;
      cnt = counts[e]; row0 = (r2 & 7) * 256;
      if (row0 >= cnt) return;
      rowbase = offsets[e];
      A = Aex; B = Bex + (long)e * H_DIM * IMOE; Cc = (char*)Cex; epi = 2;
      N = H_DIM; Kld = IMOE; NT = IMOE / 64;
      col0 = (r2 >> 3) * 256;
    }
  }

  __shared__ unsigned short lds8[65536];   // 128 KiB

  int tid = threadIdx.x, wave = tid >> 6, lane = tid & 63;
  int wr = wave >> 2, wc = wave & 3;
  int fr = lane & 15, fg = lane >> 4;

  // asm ds_read base addresses (BYTES, 32-bit LDS space)
  unsigned ldsbase = (unsigned)(size_t)lds8;
  unsigned sK0 = (unsigned)(((fg) ^ (fr & 7)) * 16);
  unsigned sK1 = (unsigned)(((4 + fg) ^ (fr & 7)) * 16);
  unsigned aBk0 = ldsbase + (unsigned)(wr * 16384 + fr * 128) + sK0;
  unsigned aBk1 = ldsbase + (unsigned)(wr * 16384 + fr * 128) + sK1;
  unsigned bBk0 = ldsbase + 65536u + (unsigned)((wc >> 1) * 16384 + (wc & 1) * 8192 + fr * 128) + sK0;
  unsigned bBk1 = ldsbase + 65536u + (unsigned)((wc >> 1) * 16384 + (wc & 1) * 8192 + fr * 128) + sK1;

  // staging source pointers [half][site], inverse-swizzled granule
  const unsigned short *pA[2][2], *pB[2][2];
#pragma unroll
  for (int h = 0; h < 2; h++)
#pragma unroll
    for (int s = 0; s < 2; s++) {
      int hr = s * 64 + wave * 8 + (lane >> 3);
      int g = (lane & 7) ^ (hr & 7);
      long ra = row0 + h * 128 + hr;
      if (ra > cnt - 1) ra = cnt - 1;           // clamp (expert tails)
      ra += rowbase;
      pA[h][s] = A + ra * (long)Kld + k0 + g * 8;
      pB[h][s] = B + (long)(col0 + h * 128 + hr) * Kld + k0 + g * 8;
    }

#define STG_A(d, h, tile) do { long ko = (long)(tile) * 64; \
    gload_lds16(pA[h][0] + ko, &lds8[(d)*16384 + (h)*8192 + wave*512]); \
    gload_lds16(pA[h][1] + ko, &lds8[(d)*16384 + (h)*8192 + 4096 + wave*512]); } while (0)
#define STG_B(d, h, tile) do { long ko = (long)(tile) * 64; \
    gload_lds16(pB[h][0] + ko, &lds8[32768 + (d)*16384 + (h)*8192 + wave*512]); \
    gload_lds16(pB[h][1] + ko, &lds8[32768 + (d)*16384 + (h)*8192 + 4096 + wave*512]); } while (0)

  short8 aReg[4][2], bReg[4][2];
  f32x4 acc[8][4] = {};

#define LDA(mh, d) do { _Pragma("unroll") for (int mi = 0; mi < 4; mi++) { \
      DSR(aReg[mi][0], aBk0 + (unsigned)((d)*32768 + ((mh)*4 + mi)*2048)); \
      DSR(aReg[mi][1], aBk1 + (unsigned)((d)*32768 + ((mh)*4 + mi)*2048)); } } while (0)
#define LDB(nh, d) do { _Pragma("unroll") for (int ni = 0; ni < 2; ni++) { \
      DSR(bReg[(nh)*2 + ni][0], bBk0 + (unsigned)((d)*32768 + ((nh)*2 + ni)*2048)); \
      DSR(bReg[(nh)*2 + ni][1], bBk1 + (unsigned)((d)*32768 + ((nh)*2 + ni)*2048)); } } while (0)
#define MM(mh, nh) do { _Pragma("unroll") for (int mi = 0; mi < 4; mi++) \
    _Pragma("unroll") for (int ni = 0; ni < 2; ni++) \
    _Pragma("unroll") for (int k = 0; k < 2; k++) \
      acc[(mh)*4 + mi][(nh)*2 + ni] = \
          MFMA16(aReg[mi][k], bReg[(nh)*2 + ni][k], acc[(mh)*4 + mi][(nh)*2 + ni]); } while (0)
#define PH_MID() do { SBAR(); LGKM0(); __builtin_amdgcn_sched_barrier(0); \
                      __builtin_amdgcn_s_setprio(1); } while (0)
#define PH_END() do { __builtin_amdgcn_s_setprio(0); SBAR(); } while (0)

  // prologue: stage dbuf0 (tile 0) + B dbuf1 (tile 1); wait dbuf0 resident
  STG_B(0, 0, 0); STG_B(0, 1, 0);
  STG_A(0, 0, 0); STG_A(0, 1, 0);
  STG_B(1, 0, 1); STG_B(1, 1, 1);
  VMCNT(4);
  SBAR();

  int NI = NT >> 1;
  for (int i = 0; i < NI; i++) {
    int t1 = 2 * i + 1;
    int t2 = 2 * i + 2; if (t2 > NT - 1) t2 = NT - 1;
    int t3 = 2 * i + 3; if (t3 > NT - 1) t3 = NT - 1;
    // ph0
    LDA(0, 0); LDB(0, 0); STG_A(1, 0, t1);
    PH_MID(); MM(0, 0); PH_END();
    // ph1
    LDB(1, 0); STG_A(1, 1, t1);
    PH_MID(); MM(0, 1); PH_END();
    // ph2
    LDA(1, 0); STG_B(0, 0, t2);
    PH_MID(); MM(1, 0); PH_END();
    // ph3
    STG_B(0, 1, t2);
    PH_MID(); MM(1, 1);
    __builtin_amdgcn_s_setprio(0); VMCNT(4); SBAR();
    // ph4
    LDA(0, 1); LDB(0, 1); STG_A(0, 0, t2);
    PH_MID(); MM(0, 0); PH_END();
    // ph5
    LDB(1, 1); STG_A(0, 1, t2);
    PH_MID(); MM(0, 1); PH_END();
    // ph6
    LDA(1, 1); STG_B(1, 0, t3);
    PH_MID(); MM(1, 0); PH_END();
    // ph7
    STG_B(1, 1, t3);
    PH_MID(); MM(1, 1);
    __builtin_amdgcn_s_setprio(0); VMCNT(4); SBAR();
  }
  VMCNT(0);   // drain tail stages before exit (protect next block's LDS)

  // ---- epilogue ----
  int rowguard = cnt - row0;
#pragma unroll
  for (int m = 0; m < 8; m++) {
    int rl = wr * 128 + m * 16 + fg * 4;
#pragma unroll
    for (int n = 0; n < 4; n++) {
      int cg = col0 + wc * 64 + n * 16 + fr;
      f32x4 v = acc[m][n];
#pragma unroll
      for (int j = 0; j < 4; j++) {
        int r = rl + j;
        if (r < rowguard) {
          long orow = (long)rowbase + row0 + r;
          long ci = orow * (long)N + cg;
          if (epi == 0)      ((unsigned short*)Cc)[ci] = f2bf(v[j]);
          else if (epi == 1) unsafeAtomicAdd(&((float*)Cc)[ci], v[j] * rowscale[orow]);
          else               ((float*)Cc)[ci] = v[j];
        }
      }
    }
  }
#undef STG_A
#undef STG_B
#undef LDA
#undef LDB
#undef MM
#undef PH_MID
#undef PH_END
}

// ---------------- elementwise ----------------

__global__ __launch_bounds__(256)
void silu2_kernel(const unsigned short* __restrict__ gu_sh, unsigned short* __restrict__ h_sh,
                  const unsigned short* __restrict__ gu_e, unsigned short* __restrict__ h_e) {
  int i = blockIdx.x * 256 + threadIdx.x;
  const int nsh = T_TOK * (ISH / 4);
  const unsigned short* g;
  unsigned short* h;
  int I, row, c4;
  if (i < nsh) {
    g = gu_sh; h = h_sh; I = ISH;
    row = i / (ISH / 4); c4 = i - row * (ISH / 4);
  } else {
    int j = i - nsh;
    g = gu_e; h = h_e; I = IMOE;
    row = j / (IMOE / 4); c4 = j - row * (IMOE / 4);
  }
  const unsigned short* gp = g + (long)row * 2 * I + c4 * 4;
  ushort4 gv = *(const ushort4*)gp;
  ushort4 uv = *(const ushort4*)(gp + I);
  ushort4 o2;
  o2.x = f2bf(silu_f(bf2f(gv.x)) * bf2f(uv.x));
  o2.y = f2bf(silu_f(bf2f(gv.y)) * bf2f(uv.y));
  o2.z = f2bf(silu_f(bf2f(gv.z)) * bf2f(uv.z));
  o2.w = f2bf(silu_f(bf2f(gv.w)) * bf2f(uv.w));
  *(ushort4*)(h + (long)row * I + c4 * 4) = o2;
}

// out = out(shared, gated, atomically accumulated) + w0*eo[s0] + w1*eo[s1]
__global__ __launch_bounds__(256)
void combine_kernel(float* __restrict__ out, const float* __restrict__ eo,
                    const int* __restrict__ slot_of_tok, const float* __restrict__ rw) {
  int i = blockIdx.x * 256 + threadIdx.x;
  const int h4n = H_DIM / 4;
  if (i >= T_TOK * h4n) return;
  int t = i / h4n;
  int h4 = i - t * h4n;
  int s0 = slot_of_tok[t * 2], s1 = slot_of_tok[t * 2 + 1];
  float w0 = rw[t * 2], w1 = rw[t * 2 + 1];
  float4 o = ((float4*)out)[i];
  float4 a = ((const float4*)eo)[(long)s0 * h4n + h4];
  float4 b = ((const float4*)eo)[(long)s1 * h4n + h4];
  o.x += w0 * a.x + w1 * b.x;
  o.y += w0 * a.y + w1 * b.y;
  o.z += w0 * a.z + w1 * b.z;
  o.w += w0 * a.w + w1 * b.w;
  ((float4*)out)[i] = o;
}

// ---------------- host ----------------

extern "C" void kernel_launch(void* const* d_in, const int* in_sizes, int n_in,
                              void* d_out, int out_size, void* d_ws, size_t ws_size,
                              hipStream_t stream) {
  (void)in_sizes; (void)n_in; (void)out_size;
  const float* x    = (const float*)d_in[0];
  const float* Wr   = (const float*)d_in[1];
  const float* Wsg  = (const float*)d_in[2];
  const float* Wsgu = (const float*)d_in[3];
  const float* Wsd  = (const float*)d_in[4];
  const float* Wegu = (const float*)d_in[5];
  const float* Wed  = (const float*)d_in[6];
  float* out = (float*)d_out;

  char* ws = (char*)d_ws;
  size_t off = 0;
  auto alloc = [&](size_t b) { size_t o = off; off += (b + 255) & ~(size_t)255; return o; };

  size_t o_xbf   = alloc((size_t)T_TOK * H_DIM * 2);
  size_t o_WsguT = alloc((size_t)2 * ISH * H_DIM * 2);          // aliased as eo in phase 1
  size_t o_WsdT  = alloc((size_t)H_DIM * ISH * 2);
  size_t o_WeguT = alloc((size_t)NEXP * 2 * IMOE * H_DIM * 2);  // h_e aliases after phase 0
  size_t o_WedT  = alloc((size_t)NEXP * H_DIM * IMOE * 2);
  size_t o_gush  = alloc((size_t)T_TOK * 2 * ISH * 2);
  size_t o_hsh   = alloc((size_t)T_TOK * ISH * 2);
  size_t o_gue   = alloc((size_t)TK_TOT * 2 * IMOE * 2);
  size_t o_xg    = alloc((size_t)TK_TOT * H_DIM * 2);
  size_t o_ints  = alloc(256);
  size_t o_rw    = alloc((size_t)TK_TOT * 4);
  size_t o_sel   = alloc((size_t)TK_TOT * 4);
  size_t o_sg    = alloc((size_t)T_TOK * 4);
  size_t o_tok   = alloc((size_t)TK_TOT * 4);
  size_t o_s2t   = alloc((size_t)TK_TOT * 4);

  if (off > ws_size) {
    fprintf(stderr, "[moe kernel] workspace too small: need %zu have %zu\n", off, ws_size);
    return;
  }

  unsigned short* xbf   = (unsigned short*)(ws + o_xbf);
  unsigned short* WsguT = (unsigned short*)(ws + o_WsguT);
  unsigned short* WsdT  = (unsigned short*)(ws + o_WsdT);
  unsigned short* WeguT = (unsigned short*)(ws + o_WeguT);
  unsigned short* WedT  = (unsigned short*)(ws + o_WedT);
  unsigned short* gu_sh = (unsigned short*)(ws + o_gush);
  unsigned short* h_sh  = (unsigned short*)(ws + o_hsh);
  unsigned short* gu_e  = (unsigned short*)(ws + o_gue);
  unsigned short* xg    = (unsigned short*)(ws + o_xg);
  unsigned short* h_e   = (unsigned short*)(ws + o_WeguT);   // alias: dead after phase 0
  float* eo             = (float*)(ws + o_WsguT);            // alias: dead after phase 0

  int* counts  = (int*)(ws + o_ints);
  int* cursor  = counts + 8;
  int* offsets = counts + 16;
  float* rw    = (float*)(ws + o_rw);
  int* sel     = (int*)(ws + o_sel);
  float* sgate = (float*)(ws + o_sg);
  int* tok     = (int*)(ws + o_tok);
  int* s2t     = (int*)(ws + o_s2t);

  dim3 tb(32, 8, 1);

  hipMemsetAsync(counts, 0, 64, stream);
  hipMemsetAsync(out, 0, (size_t)T_TOK * H_DIM * 4, stream);   // atomic target

  transpose_cvt_kernel<<<dim3(2 * ISH / 32, H_DIM / 32, 1), tb, 0, stream>>>(
      Wsgu, WsguT, H_DIM, 2 * ISH, 0, 0);
  transpose_cvt_kernel<<<dim3(H_DIM / 32, ISH / 32, 1), tb, 0, stream>>>(
      Wsd, WsdT, ISH, H_DIM, 0, 0);
  transpose_cvt_kernel<<<dim3(2 * IMOE / 32, H_DIM / 32, NEXP), tb, 0, stream>>>(
      Wegu, WeguT, H_DIM, 2 * IMOE, (long)H_DIM * 2 * IMOE, (long)2 * IMOE * H_DIM);
  transpose_cvt_kernel<<<dim3(H_DIM / 32, IMOE / 32, NEXP), tb, 0, stream>>>(
      Wed, WedT, IMOE, H_DIM, (long)IMOE * H_DIM, (long)H_DIM * IMOE);

  cvt_x_kernel<<<(T_TOK * H_DIM / 4) / 256, 256, 0, stream>>>(x, xbf, T_TOK * H_DIM / 4);

  router_kernel<<<T_TOK, 256, 0, stream>>>(x, Wr, Wsg, rw, sel, sgate, counts);
  scan_kernel<<<1, 64, 0, stream>>>(counts, offsets);
  scatter_kernel<<<(T_TOK + 255) / 256, 256, 0, stream>>>(sel, offsets, cursor, tok, s2t);
  gather_kernel<<<TK_TOT, 256, 0, stream>>>(xbf, tok, xg);

  // fused gate-up: shared (352) + experts (8 x 88) = 1056 blocks
  moe_gemm8_kernel<0><<<1056, 512, 0, stream>>>(
      xbf, WsguT, xg, WeguT, gu_sh, gu_e, counts, offsets, nullptr);

  {
    int total = T_TOK * (ISH / 4) + TK_TOT * (IMOE / 4);
    silu2_kernel<<<total / 256, 256, 0, stream>>>(gu_sh, h_sh, gu_e, h_e);
  }

  // fused down: shared split-K4 atomic (256) + experts (8 x 64) = 768 blocks
  moe_gemm8_kernel<1><<<768, 512, 0, stream>>>(
      h_sh, WsdT, h_e, WedT, out, eo, counts, offsets, sgate);

  combine_kernel<<<(T_TOK * H_DIM / 4) / 256, 256, 0, stream>>>(out, eo, s2t, rw);
}

// Round 6
// 861.779 us; speedup vs baseline: 1.0225x; 1.0225x over previous
//
#include <hip/hip_runtime.h>
#include <cstdio>

// Qwen2 MoE sparse block, MI355X gfx950.
// Round 6: (1) site-granular staging (16 x 1-op stages / 8-phase iter) so
// vmcnt(6) enforces loads issued 4-7 phases earlier (true m201 depth);
// (2) persistent-block GEMMs with device-built job queue (no dead blocks,
// greedy balance); (3) shared-down split-K=2 into f32 partial buffers summed
// in combine (no atomics). asm ds_read K-loop kept (R5 evidence: +MfmaUtil).

#define H_DIM 2048
#define IMOE  1408
#define ISH   5632
#define NEXP  8
#define T_TOK 2048
#define TK_TOT (T_TOK * 2)

typedef __attribute__((ext_vector_type(8))) short short8;
typedef __attribute__((ext_vector_type(8))) __bf16 bf16x8;
typedef __attribute__((ext_vector_type(4))) float f32x4;

__device__ __forceinline__ float bf2f(unsigned short u) {
  union { unsigned int i; float f; } v; v.i = ((unsigned int)u) << 16; return v.f;
}
__device__ __forceinline__ unsigned short f2bf(float f) {
  union { float f; unsigned int i; } v; v.f = f;
  unsigned int x = v.i;
  return (unsigned short)((x + 0x7fffu + ((x >> 16) & 1u)) >> 16);
}

__device__ __forceinline__ f32x4 MFMA16(short8 a, short8 b, f32x4 c) {
  return __builtin_amdgcn_mfma_f32_16x16x32_bf16(
      __builtin_bit_cast(bf16x8, a), __builtin_bit_cast(bf16x8, b), c, 0, 0, 0);
}

__device__ __forceinline__ void gload_lds16(const unsigned short* g, unsigned short* l) {
  __builtin_amdgcn_global_load_lds(
      (const __attribute__((address_space(1))) unsigned int*)g,
      (__attribute__((address_space(3))) unsigned int*)l, 16, 0, 0);
}

__device__ __forceinline__ float silu_f(float x) { return x / (1.0f + __expf(-x)); }

#define SBAR()   asm volatile("s_barrier" ::: "memory")
#define VMCNT(n) asm volatile("s_waitcnt vmcnt(" #n ")" ::: "memory")
#define LGKM0()  asm volatile("s_waitcnt lgkmcnt(0)" ::: "memory")
#define DSR(dst, a) asm volatile("ds_read_b128 %0, %1" : "=v"(dst) : "v"(a))

// ---------------- conversion kernels ----------------

__global__ __launch_bounds__(256)
void transpose_cvt_kernel(const float* __restrict__ src, unsigned short* __restrict__ dst,
                          int R, int C, long sStride, long dStride) {
  src += (long)blockIdx.z * sStride;
  dst += (long)blockIdx.z * dStride;
  __shared__ float tile[32][33];
  int tx = threadIdx.x, ty = threadIdx.y;           // 32 x 8
  int x = blockIdx.x * 32 + tx;
  int yb = blockIdx.y * 32;
#pragma unroll
  for (int j = 0; j < 4; j++) {
    int y = yb + ty + j * 8;
    tile[ty + j * 8][tx] = src[(long)y * C + x];
  }
  __syncthreads();
  int c = blockIdx.x * 32 + ty;
  int r = yb + tx;
#pragma unroll
  for (int j = 0; j < 4; j++) {
    dst[(long)(c + j * 8) * R + r] = f2bf(tile[tx][ty + j * 8]);
  }
}

__global__ __launch_bounds__(256)
void cvt_x_kernel(const float* __restrict__ x, unsigned short* __restrict__ xb, int total4) {
  int i = blockIdx.x * 256 + threadIdx.x;
  if (i >= total4) return;
  float4 v = ((const float4*)x)[i];
  ushort4 o;
  o.x = f2bf(v.x); o.y = f2bf(v.y); o.z = f2bf(v.z); o.w = f2bf(v.w);
  ((ushort4*)xb)[i] = o;
}

// ---------------- routing ----------------

__global__ __launch_bounds__(256)
void router_kernel(const float* __restrict__ x, const float* __restrict__ Wr,
                   const float* __restrict__ Wsg, float* __restrict__ rw,
                   int* __restrict__ sel, float* __restrict__ sgate_sig,
                   int* __restrict__ counts) {
  int t = blockIdx.x;
  const float* xr = x + (long)t * H_DIM;
  float p[9];
#pragma unroll
  for (int e = 0; e < 9; e++) p[e] = 0.0f;
  for (int h = threadIdx.x; h < H_DIM; h += 256) {
    float xv = xr[h];
#pragma unroll
    for (int e = 0; e < 8; e++) p[e] += xv * Wr[e * H_DIM + h];
    p[8] += xv * Wsg[h];
  }
#pragma unroll
  for (int e = 0; e < 9; e++)
    for (int off = 32; off > 0; off >>= 1)
      p[e] += __shfl_down(p[e], off, 64);
  __shared__ float red[4][9];
  int wave = threadIdx.x >> 6, lane = threadIdx.x & 63;
  if (lane == 0) {
#pragma unroll
    for (int e = 0; e < 9; e++) red[wave][e] = p[e];
  }
  __syncthreads();
  if (threadIdx.x == 0) {
    float lg[9];
#pragma unroll
    for (int e = 0; e < 9; e++) lg[e] = red[0][e] + red[1][e] + red[2][e] + red[3][e];
    float m = lg[0];
#pragma unroll
    for (int e = 1; e < 8; e++) m = fmaxf(m, lg[e]);
    float pr[8], s = 0.0f;
#pragma unroll
    for (int e = 0; e < 8; e++) { pr[e] = expf(lg[e] - m); s += pr[e]; }
    float inv = 1.0f / s;
#pragma unroll
    for (int e = 0; e < 8; e++) pr[e] *= inv;
    int i0 = 0;
#pragma unroll
    for (int e = 1; e < 8; e++) if (pr[e] > pr[i0]) i0 = e;
    int i1 = (i0 == 0) ? 1 : 0;
#pragma unroll
    for (int e = 0; e < 8; e++) if (e != i0 && pr[e] > pr[i1]) i1 = e;
    rw[t * 2] = pr[i0]; rw[t * 2 + 1] = pr[i1];
    sel[t * 2] = i0;    sel[t * 2 + 1] = i1;
    sgate_sig[t] = 1.0f / (1.0f + expf(-lg[8]));
    atomicAdd(&counts[i0], 1);
    atomicAdd(&counts[i1], 1);
  }
}

__global__ void scan_kernel(const int* __restrict__ counts, int* __restrict__ offsets) {
  if (threadIdx.x == 0 && blockIdx.x == 0) {
    int s = 0;
    for (int e = 0; e < NEXP; e++) { offsets[e] = s; s += counts[e]; }
    offsets[NEXP] = s;
  }
}

__global__ __launch_bounds__(256)
void scatter_kernel(const int* __restrict__ sel, const int* __restrict__ offsets,
                    int* __restrict__ cursor, int* __restrict__ tok_of_slot,
                    int* __restrict__ slot_of_tok) {
  int t = blockIdx.x * 256 + threadIdx.x;
  if (t >= T_TOK) return;
#pragma unroll
  for (int k = 0; k < 2; k++) {
    int e = sel[t * 2 + k];
    int pos = atomicAdd(&cursor[e], 1);
    int slot = offsets[e] + pos;
    tok_of_slot[slot] = t;
    slot_of_tok[t * 2 + k] = slot;
  }
}

__global__ __launch_bounds__(256)
void gather_kernel(const unsigned short* __restrict__ xbf, const int* __restrict__ tok,
                   unsigned short* __restrict__ xg) {
  int i = blockIdx.x * 256 + threadIdx.x;   // slot*256 + col16B
  int slot = i >> 8, c8 = i & 255;
  long src = (long)tok[slot] * H_DIM + c8 * 8;
  ulonglong2 v = *(const ulonglong2*)(xbf + src);
  ((ulonglong2*)xg)[i] = v;
}

// job encoding: kind<<28 | e<<24 | ks<<20 | row<<8 | col
// kind 0: P0 shared gate-up   kind 1: P0 expert gate-up
// kind 2: P1 shared down (split-K ks)   kind 3: P1 expert down
__global__ void build_jobs_kernel(const int* __restrict__ counts, int* __restrict__ meta,
                                  int* __restrict__ jobs0, int* __restrict__ jobs1) {
  if (threadIdx.x != 0 || blockIdx.x != 0) return;
  int n0 = 0, n1 = 0;
  for (int c = 0; c < 44; c++)
    for (int r = 0; r < 8; r++) jobs0[n0++] = (0 << 28) | (r << 8) | c;
  for (int e = 0; e < NEXP; e++) {
    int rows = (counts[e] + 255) >> 8;
    for (int c = 0; c < 11; c++)
      for (int r = 0; r < rows; r++)
        jobs0[n0++] = (1 << 28) | (e << 24) | (r << 8) | c;
  }
  // P1: long (NT=44) shared jobs first for greedy balance
  for (int ks = 0; ks < 2; ks++)
    for (int c = 0; c < 8; c++)
      for (int r = 0; r < 8; r++)
        jobs1[n1++] = (2 << 28) | (ks << 20) | (r << 8) | c;
  for (int e = 0; e < NEXP; e++) {
    int rows = (counts[e] + 255) >> 8;
    for (int c = 0; c < 8; c++)
      for (int r = 0; r < rows; r++)
        jobs1[n1++] = (3 << 28) | (e << 24) | (r << 8) | c;
  }
  meta[34] = n0; meta[35] = n1;
}

// ---------------- persistent 256x256 8-phase GEMM ----------------
// 512 thr = 8 waves (2M x 4N). BK=64. LDS per operand: [2dbuf][2half][2site]
// [64rows][64k] bf16 (site-granular stages: 1 gload_lds = 8KB site).
// Stage schedule (2 stage-ops/phase), waits vmcnt(6) at ph3/ph7 only;
// every staged site completes 4-7 phases before its enforcing wait.
template <int PHASE>
__global__ __launch_bounds__(512, 2)
void moe_gemm_p(const unsigned short* __restrict__ Ash,
                const unsigned short* __restrict__ Bsh,
                const unsigned short* __restrict__ Aex,
                const unsigned short* __restrict__ Bex,
                void* __restrict__ Csh, void* __restrict__ Cex,
                const int* __restrict__ counts, const int* __restrict__ offsets,
                const int* __restrict__ jobs, int* __restrict__ qhead,
                const int* __restrict__ meta) {
  __shared__ unsigned short lds8[65536];   // 128 KiB
  __shared__ int jsh;

  int tid = threadIdx.x, wave = tid >> 6, lane = tid & 63;
  int wr = wave >> 2, wc = wave & 3;
  int fr = lane & 15, fg = lane >> 4;

  unsigned ldsbase = (unsigned)(size_t)lds8;
  unsigned sK0 = (unsigned)(((fg) ^ (fr & 7)) * 16);
  unsigned sK1 = (unsigned)(((4 + fg) ^ (fr & 7)) * 16);
  unsigned aBk0 = ldsbase + (unsigned)(wr * 16384 + fr * 128) + sK0;
  unsigned aBk1 = ldsbase + (unsigned)(wr * 16384 + fr * 128) + sK1;
  unsigned bBk0 = ldsbase + 65536u + (unsigned)((wc >> 1) * 16384 + (wc & 1) * 8192 + fr * 128) + sK0;
  unsigned bBk1 = ldsbase + 65536u + (unsigned)((wc >> 1) * 16384 + (wc & 1) * 8192 + fr * 128) + sK1;

  int qcnt = meta[PHASE ? 35 : 34];

  for (;;) {
    __syncthreads();
    if (tid == 0) jsh = atomicAdd(qhead, 1);
    __syncthreads();
    if (jsh >= qcnt) break;
    int job = jobs[jsh];

    int kind = (job >> 28) & 3, e = (job >> 24) & 15, ks = (job >> 20) & 3;
    int row0 = ((job >> 8) & 255) << 8;
    int col0 = (job & 255) << 8;
    const unsigned short *A, *B;
    char* Cc;
    int N, Kld, NT, k0 = 0, cnt = T_TOK, rowbase = 0;
    if constexpr (PHASE == 0) {
      if (kind == 0) { A = Ash; B = Bsh; Cc = (char*)Csh; N = 2 * ISH; Kld = H_DIM; NT = 32; }
      else {
        cnt = counts[e]; rowbase = offsets[e];
        A = Aex; B = Bex + (long)e * (2 * IMOE) * H_DIM; Cc = (char*)Cex;
        N = 2 * IMOE; Kld = H_DIM; NT = 32;
      }
    } else {
      if (kind == 2) {
        A = Ash; B = Bsh; Cc = (char*)Csh + (size_t)ks * ((size_t)T_TOK * H_DIM * 4);
        N = H_DIM; Kld = ISH; NT = 44; k0 = ks * (ISH / 2);
      } else {
        cnt = counts[e]; rowbase = offsets[e];
        A = Aex; B = Bex + (long)e * H_DIM * IMOE; Cc = (char*)Cex;
        N = H_DIM; Kld = IMOE; NT = 22;
      }
    }

    // staging source pointers [half][site], inverse-swizzled 16B granule
    const unsigned short *pA[2][2], *pB[2][2];
#pragma unroll
    for (int h = 0; h < 2; h++)
#pragma unroll
      for (int s = 0; s < 2; s++) {
        int hr = s * 64 + wave * 8 + (lane >> 3);
        int g = (lane & 7) ^ (hr & 7);
        long ra = row0 + h * 128 + hr;
        if (ra > cnt - 1) ra = cnt - 1;
        ra += rowbase;
        pA[h][s] = A + ra * (long)Kld + k0 + g * 8;
        pB[h][s] = B + (long)(col0 + h * 128 + hr) * Kld + k0 + g * 8;
      }

#define SGA(d, h, s, t) gload_lds16(pA[h][s] + (long)(t) * 64, \
      &lds8[(d) * 16384 + (h) * 8192 + (s) * 4096 + wave * 512])
#define SGB(d, h, s, t) gload_lds16(pB[h][s] + (long)(t) * 64, \
      &lds8[32768 + (d) * 16384 + (h) * 8192 + (s) * 4096 + wave * 512])

    short8 aReg[4][2], bReg[4][2];
    f32x4 acc[8][4] = {};

#define LDA(mh, d) do { _Pragma("unroll") for (int mi = 0; mi < 4; mi++) { \
      DSR(aReg[mi][0], aBk0 + (unsigned)((d)*32768 + ((mh)*4 + mi)*2048)); \
      DSR(aReg[mi][1], aBk1 + (unsigned)((d)*32768 + ((mh)*4 + mi)*2048)); } } while (0)
#define LDB(nh, d) do { _Pragma("unroll") for (int ni = 0; ni < 2; ni++) { \
      DSR(bReg[(nh)*2 + ni][0], bBk0 + (unsigned)((d)*32768 + ((nh)*2 + ni)*2048)); \
      DSR(bReg[(nh)*2 + ni][1], bBk1 + (unsigned)((d)*32768 + ((nh)*2 + ni)*2048)); } } while (0)
#define MM(mh, nh) do { _Pragma("unroll") for (int mi = 0; mi < 4; mi++) \
    _Pragma("unroll") for (int ni = 0; ni < 2; ni++) \
    _Pragma("unroll") for (int k = 0; k < 2; k++) \
      acc[(mh)*4 + mi][(nh)*2 + ni] = \
          MFMA16(aReg[mi][k], bReg[(nh)*2 + ni][k], acc[(mh)*4 + mi][(nh)*2 + ni]); } while (0)
#define PH_MID() do { SBAR(); LGKM0(); __builtin_amdgcn_sched_barrier(0); \
                      __builtin_amdgcn_s_setprio(1); } while (0)
#define PH_END() do { __builtin_amdgcn_s_setprio(0); SBAR(); } while (0)

    // prologue: d0 (tile 0) fully, d1 (tile 1) minus B-s1 (staged at ph0)
    SGA(0, 0, 0, 0); SGA(0, 1, 0, 0); SGA(0, 0, 1, 0); SGA(0, 1, 1, 0);
    SGB(0, 0, 0, 0); SGB(0, 1, 0, 0); SGB(0, 0, 1, 0); SGB(0, 1, 1, 0);
    SGA(1, 0, 0, 1); SGA(1, 1, 0, 1);
    SGB(1, 0, 0, 1); SGB(1, 1, 0, 1);
    SGA(1, 0, 1, 1); SGA(1, 1, 1, 1);
    VMCNT(6);
    SBAR();

    int NI = NT >> 1;
    for (int i = 0; i < NI; i++) {
      int td1 = 2 * i + 1;
      int t2 = 2 * i + 2; if (t2 > NT - 1) t2 = NT - 1;
      int t3 = 2 * i + 3; if (t3 > NT - 1) t3 = NT - 1;
      // ph0
      LDA(0, 0); LDB(0, 0); SGB(1, 0, 1, td1); SGB(1, 1, 1, td1);
      PH_MID(); MM(0, 0); PH_END();
      // ph1
      LDB(1, 0); SGA(0, 0, 0, t2); SGA(0, 1, 0, t2);
      PH_MID(); MM(0, 1); PH_END();
      // ph2
      LDA(1, 0); SGB(0, 0, 0, t2); SGB(0, 1, 0, t2);
      PH_MID(); MM(1, 0); PH_END();
      // ph3
      SGB(0, 0, 1, t2); SGB(0, 1, 1, t2);
      PH_MID(); MM(1, 1);
      __builtin_amdgcn_s_setprio(0); VMCNT(6); SBAR();
      // ph4
      LDA(0, 1); LDB(0, 1); SGA(0, 0, 1, t2); SGA(0, 1, 1, t2);
      PH_MID(); MM(0, 0); PH_END();
      // ph5
      LDB(1, 1); SGA(1, 0, 0, t3); SGA(1, 1, 0, t3);
      PH_MID(); MM(0, 1); PH_END();
      // ph6
      LDA(1, 1); SGB(1, 0, 0, t3); SGB(1, 1, 0, t3);
      PH_MID(); MM(1, 0); PH_END();
      // ph7
      SGA(1, 0, 1, t3); SGA(1, 1, 1, t3);
      PH_MID(); MM(1, 1);
      __builtin_amdgcn_s_setprio(0); VMCNT(6); SBAR();
    }
    VMCNT(0);

    // epilogue
    int rowguard = cnt - row0;
#pragma unroll
    for (int m = 0; m < 8; m++) {
      int rl = wr * 128 + m * 16 + fg * 4;
#pragma unroll
      for (int n = 0; n < 4; n++) {
        int cg = col0 + wc * 64 + n * 16 + fr;
        f32x4 v = acc[m][n];
#pragma unroll
        for (int j = 0; j < 4; j++) {
          int r = rl + j;
          if (r < rowguard) {
            long orow = (long)rowbase + row0 + r;
            long ci = orow * (long)N + cg;
            if constexpr (PHASE == 0) ((unsigned short*)Cc)[ci] = f2bf(v[j]);
            else                      ((float*)Cc)[ci] = v[j];
          }
        }
      }
    }
#undef SGA
#undef SGB
#undef LDA
#undef LDB
#undef MM
#undef PH_MID
#undef PH_END
  }
}

// ---------------- elementwise ----------------

__global__ __launch_bounds__(256)
void silu2_kernel(const unsigned short* __restrict__ gu_sh, unsigned short* __restrict__ h_sh,
                  const unsigned short* __restrict__ gu_e, unsigned short* __restrict__ h_e) {
  int i = blockIdx.x * 256 + threadIdx.x;
  const int nsh = T_TOK * (ISH / 4);
  const unsigned short* g;
  unsigned short* h;
  int I, row, c4;
  if (i < nsh) {
    g = gu_sh; h = h_sh; I = ISH;
    row = i / (ISH / 4); c4 = i - row * (ISH / 4);
  } else {
    int j = i - nsh;
    g = gu_e; h = h_e; I = IMOE;
    row = j / (IMOE / 4); c4 = j - row * (IMOE / 4);
  }
  const unsigned short* gp = g + (long)row * 2 * I + c4 * 4;
  ushort4 gv = *(const ushort4*)gp;
  ushort4 uv = *(const ushort4*)(gp + I);
  ushort4 o2;
  o2.x = f2bf(silu_f(bf2f(gv.x)) * bf2f(uv.x));
  o2.y = f2bf(silu_f(bf2f(gv.y)) * bf2f(uv.y));
  o2.z = f2bf(silu_f(bf2f(gv.z)) * bf2f(uv.z));
  o2.w = f2bf(silu_f(bf2f(gv.w)) * bf2f(uv.w));
  *(ushort4*)(h + (long)row * I + c4 * 4) = o2;
}

// out = sgate[t]*(sp0+sp1) + w0*eo[s0] + w1*eo[s1]
__global__ __launch_bounds__(256)
void combine_kernel(float* __restrict__ out, const float* __restrict__ sp,
                    const float* __restrict__ eo, const int* __restrict__ slot_of_tok,
                    const float* __restrict__ rw, const float* __restrict__ sgate) {
  int i = blockIdx.x * 256 + threadIdx.x;
  const int h4n = H_DIM / 4;
  if (i >= T_TOK * h4n) return;
  int t = i / h4n;
  int h4 = i - t * h4n;
  int s0 = slot_of_tok[t * 2], s1 = slot_of_tok[t * 2 + 1];
  float w0 = rw[t * 2], w1 = rw[t * 2 + 1];
  float sg = sgate[t];
  float4 p0 = ((const float4*)sp)[i];
  float4 p1 = ((const float4*)sp)[(T_TOK * H_DIM / 4) + i];
  float4 a = ((const float4*)eo)[(long)s0 * h4n + h4];
  float4 b = ((const float4*)eo)[(long)s1 * h4n + h4];
  float4 o;
  o.x = sg * (p0.x + p1.x) + w0 * a.x + w1 * b.x;
  o.y = sg * (p0.y + p1.y) + w0 * a.y + w1 * b.y;
  o.z = sg * (p0.z + p1.z) + w0 * a.z + w1 * b.z;
  o.w = sg * (p0.w + p1.w) + w0 * a.w + w1 * b.w;
  ((float4*)out)[i] = o;
}

// ---------------- host ----------------

extern "C" void kernel_launch(void* const* d_in, const int* in_sizes, int n_in,
                              void* d_out, int out_size, void* d_ws, size_t ws_size,
                              hipStream_t stream) {
  (void)in_sizes; (void)n_in; (void)out_size;
  const float* x    = (const float*)d_in[0];
  const float* Wr   = (const float*)d_in[1];
  const float* Wsg  = (const float*)d_in[2];
  const float* Wsgu = (const float*)d_in[3];
  const float* Wsd  = (const float*)d_in[4];
  const float* Wegu = (const float*)d_in[5];
  const float* Wed  = (const float*)d_in[6];
  float* out = (float*)d_out;

  char* ws = (char*)d_ws;
  size_t off = 0;
  auto alloc = [&](size_t b) { size_t o = off; off += (b + 255) & ~(size_t)255; return o; };

  size_t o_xbf   = alloc((size_t)T_TOK * H_DIM * 2);
  size_t o_WsguT = alloc((size_t)2 * ISH * H_DIM * 2);          // aliased as eo in P1
  size_t o_WsdT  = alloc((size_t)H_DIM * ISH * 2);
  size_t o_WeguT = alloc((size_t)NEXP * 2 * IMOE * H_DIM * 2);  // h_e aliases after P0
  size_t o_WedT  = alloc((size_t)NEXP * H_DIM * IMOE * 2);
  size_t o_gush  = alloc((size_t)T_TOK * 2 * ISH * 2);          // sp0/sp1 alias after silu
  size_t o_hsh   = alloc((size_t)T_TOK * ISH * 2);
  size_t o_gue   = alloc((size_t)TK_TOT * 2 * IMOE * 2);
  size_t o_xg    = alloc((size_t)TK_TOT * H_DIM * 2);
  size_t o_ints  = alloc(256);
  size_t o_rw    = alloc((size_t)TK_TOT * 4);
  size_t o_sel   = alloc((size_t)TK_TOT * 4);
  size_t o_sg    = alloc((size_t)T_TOK * 4);
  size_t o_tok   = alloc((size_t)TK_TOT * 4);
  size_t o_s2t   = alloc((size_t)TK_TOT * 4);
  size_t o_jb0   = alloc(4096 * 4);
  size_t o_jb1   = alloc(4096 * 4);

  if (off > ws_size) {
    fprintf(stderr, "[moe kernel] workspace too small: need %zu have %zu\n", off, ws_size);
    return;
  }

  unsigned short* xbf   = (unsigned short*)(ws + o_xbf);
  unsigned short* WsguT = (unsigned short*)(ws + o_WsguT);
  unsigned short* WsdT  = (unsigned short*)(ws + o_WsdT);
  unsigned short* WeguT = (unsigned short*)(ws + o_WeguT);
  unsigned short* WedT  = (unsigned short*)(ws + o_WedT);
  unsigned short* gu_sh = (unsigned short*)(ws + o_gush);
  unsigned short* h_sh  = (unsigned short*)(ws + o_hsh);
  unsigned short* gu_e  = (unsigned short*)(ws + o_gue);
  unsigned short* xg    = (unsigned short*)(ws + o_xg);
  unsigned short* h_e   = (unsigned short*)(ws + o_WeguT);   // alias: dead after P0
  float* eo             = (float*)(ws + o_WsguT);            // alias: dead after P0
  float* sp             = (float*)(ws + o_gush);             // alias: gu_sh dead after silu

  int* ints    = (int*)(ws + o_ints);
  int* counts  = ints;
  int* cursor  = ints + 8;
  int* offsets = ints + 16;
  int* qh0     = ints + 32;
  int* qh1     = ints + 33;
  float* rw    = (float*)(ws + o_rw);
  int* sel     = (int*)(ws + o_sel);
  float* sgate = (float*)(ws + o_sg);
  int* tok     = (int*)(ws + o_tok);
  int* s2t     = (int*)(ws + o_s2t);
  int* jobs0   = (int*)(ws + o_jb0);
  int* jobs1   = (int*)(ws + o_jb1);

  dim3 tb(32, 8, 1);

  hipMemsetAsync(ints, 0, 256, stream);   // counts, cursor, qheads

  transpose_cvt_kernel<<<dim3(2 * ISH / 32, H_DIM / 32, 1), tb, 0, stream>>>(
      Wsgu, WsguT, H_DIM, 2 * ISH, 0, 0);
  transpose_cvt_kernel<<<dim3(H_DIM / 32, ISH / 32, 1), tb, 0, stream>>>(
      Wsd, WsdT, ISH, H_DIM, 0, 0);
  transpose_cvt_kernel<<<dim3(2 * IMOE / 32, H_DIM / 32, NEXP), tb, 0, stream>>>(
      Wegu, WeguT, H_DIM, 2 * IMOE, (long)H_DIM * 2 * IMOE, (long)2 * IMOE * H_DIM);
  transpose_cvt_kernel<<<dim3(H_DIM / 32, IMOE / 32, NEXP), tb, 0, stream>>>(
      Wed, WedT, IMOE, H_DIM, (long)IMOE * H_DIM, (long)H_DIM * IMOE);

  cvt_x_kernel<<<(T_TOK * H_DIM / 4) / 256, 256, 0, stream>>>(x, xbf, T_TOK * H_DIM / 4);

  router_kernel<<<T_TOK, 256, 0, stream>>>(x, Wr, Wsg, rw, sel, sgate, counts);
  scan_kernel<<<1, 64, 0, stream>>>(counts, offsets);
  build_jobs_kernel<<<1, 64, 0, stream>>>(counts, ints, jobs0, jobs1);
  scatter_kernel<<<(T_TOK + 255) / 256, 256, 0, stream>>>(sel, offsets, cursor, tok, s2t);
  gather_kernel<<<TK_TOT, 256, 0, stream>>>(xbf, tok, xg);

  // P0: persistent gate-up (shared + experts)
  moe_gemm_p<0><<<256, 512, 0, stream>>>(
      xbf, WsguT, xg, WeguT, gu_sh, gu_e, counts, offsets, jobs0, qh0, ints);

  {
    int total = T_TOK * (ISH / 4) + TK_TOT * (IMOE / 4);
    silu2_kernel<<<total / 256, 256, 0, stream>>>(gu_sh, h_sh, gu_e, h_e);
  }

  // P1: persistent down (shared split-K2 -> sp, experts -> eo)
  moe_gemm_p<1><<<256, 512, 0, stream>>>(
      h_sh, WsdT, h_e, WedT, sp, eo, counts, offsets, jobs1, qh1, ints);

  combine_kernel<<<(T_TOK * H_DIM / 4) / 256, 256, 0, stream>>>(out, sp, eo, s2t, rw, sgate);
}